// Round 12
// baseline (51.433 us; speedup 1.0000x reference)
//
#include <hip/hip_runtime.h>
#include <hip/hip_bf16.h>

// out[8192,1024] = x[8192,1024] @ W[1024,1024]^T + b  (fp32 in/out, bf16 MFMA)
// v12: two kernels.
//  1) cvt_bf16: f32 -> bf16 ROW-MAJOR into d_ws (coalesced read AND write).
//  2) gemm_dma: m97 structure. 128x128 tile, BK=32, 256 thr / 4 waves (2x2,
//     wave tile 64x64), global_load_lds width-16 with per-lane pre-swizzled
//     global src -> fragment-linear LDS (conflict-free, no cvt, no ds_write,
//     no VGPR roundtrip). Double-buffered, __syncthreads per K-step (m97).
//     Grid 512 = 2 blocks/CU, XCD-exclusive m-panels (x-panel+W = 4MB = L2).
//     v10-validated transposed-C epilogue (swapped mfma operands, f32x4 stores).

typedef float f32x4 __attribute__((ext_vector_type(4)));
typedef __bf16 bf16x8 __attribute__((ext_vector_type(8)));
typedef unsigned short u16x8 __attribute__((ext_vector_type(8)));

#define MD 8192
#define ND 1024
#define KD 1024
#define BM 128
#define BN 128
#define BK 32
#define NT (KD / BK)                       // 32 K-tiles
#define XELEMS ((size_t)MD * KD)           // 8388608
#define WELEMS ((size_t)ND * KD)           // 1048576
#define WS_NEEDED ((XELEMS + WELEMS) * 2)  // 18874368 B (proven available in R9)

// ---------------- kernel 1: f32 -> bf16 row-major (fully coalesced) ----------
__global__ __launch_bounds__(256)
void cvt_bf16(const float* __restrict__ X, const float* __restrict__ W,
              unsigned short* __restrict__ ws) {
  const size_t i = (size_t)blockIdx.x * 256 + threadIdx.x;  // one 8-elem chunk
  const float* src;
  unsigned short* dst;
  if (i < XELEMS / 8) {
    src = X + i * 8;
    dst = ws + i * 8;
  } else {
    const size_t j = i - XELEMS / 8;
    src = W + j * 8;
    dst = ws + XELEMS + j * 8;
  }
  f32x4 lo = *(const f32x4*)src;
  f32x4 hi = *(const f32x4*)(src + 4);
  u16x8 o;
#pragma unroll
  for (int j = 0; j < 4; ++j) {
    o[j]     = __builtin_bit_cast(unsigned short, (__bf16)lo[j]);
    o[4 + j] = __builtin_bit_cast(unsigned short, (__bf16)hi[j]);
  }
  *(u16x8*)dst = o;
}

// ---------------- kernel 2: DMA-staged bf16 GEMM (m97 structure) -------------
__device__ __forceinline__ void dma16(const void* g, void* l) {
  __builtin_amdgcn_global_load_lds(
      (const __attribute__((address_space(1))) unsigned int*)g,
      (__attribute__((address_space(3))) unsigned int*)l, 16, 0, 0);
}

__global__ __launch_bounds__(256, 4)
void gemm_dma(const unsigned short* __restrict__ ws, const float* __restrict__ Bv,
              float* __restrict__ C) {
  // Fragment-linear LDS tile (8 KB): stripe f (16 rows) at f*1024; within:
  // lane l -> row f*16+(l&15), k = (l>>4)*8 (16B). Linear lane order ->
  // conflict-free ds_read_b128 AND valid wave-linear DMA dest.
  __shared__ __align__(16) unsigned char Alds[2][8192];
  __shared__ __align__(16) unsigned char Blds[2][8192];

  const int bid = blockIdx.x;
  const int xcd = bid & 7;                 // dispatch round-robins XCDs by bid&7
  const int ord = bid >> 3;                // 0..63
  const int mtile = xcd * 8 + (ord >> 3);  // 8 XCD-exclusive m-panels per XCD
  const int ntile = ord & 7;
  const int brow = mtile * BM;
  const int bcol = ntile * BN;

  const int t = threadIdx.x;
  const int lane = t & 63;
  const int w = t >> 6;      // 0..3
  const int wm = w >> 1;     // 0..1 : 64-row half
  const int wn = w & 1;      // 0..1 : 64-col half

  const unsigned char* xb = (const unsigned char*)ws;                    // [8192][1024] bf16
  const unsigned char* wb = (const unsigned char*)(ws + XELEMS);         // [1024][1024] bf16

  // DMA slot decode: slot = o*256 + t in [0,512); chunk c = slot>>6 (stripe),
  // lane l = slot&63 -> row = c*16 + (l&15), kq = l>>4.
  // global src (row-major bf16, row stride 2048B) = base + row*2048 + kt*64 + kq*16
  size_t srcA[2], srcB[2];
  int ldsOff[2];
#pragma unroll
  for (int o = 0; o < 2; ++o) {
    const int slot = o * 256 + t;
    const int c = slot >> 6, l = slot & 63;
    const int row = c * 16 + (l & 15), kq = l >> 4;
    srcA[o] = (size_t)(brow + row) * 2048 + kq * 16;
    srcB[o] = (size_t)(bcol + row) * 2048 + kq * 16;
    ldsOff[o] = slot * 16;
  }

#define DMA_TILE(kt, buf)                                                \
  do {                                                                   \
    _Pragma("unroll") for (int o = 0; o < 2; ++o)                        \
      dma16(xb + srcA[o] + (kt) * 64, &Alds[buf][ldsOff[o]]);            \
    _Pragma("unroll") for (int o = 0; o < 2; ++o)                        \
      dma16(wb + srcB[o] + (kt) * 64, &Blds[buf][ldsOff[o]]);            \
  } while (0)

  f32x4 acc[4][4] = {};   // transposed C/D fragments (v10-validated)

#define COMPUTE(buf)                                                           \
  do {                                                                         \
    bf16x8 bf[4];                                                              \
    _Pragma("unroll") for (int n = 0; n < 4; ++n)                              \
      bf[n] = __builtin_bit_cast(bf16x8,                                       \
          *(const u16x8*)(&Blds[buf][(wn * 4 + n) * 1024 + lane * 16]));       \
    bf16x8 am[4];                                                              \
    _Pragma("unroll") for (int m = 0; m < 4; ++m)                              \
      am[m] = __builtin_bit_cast(bf16x8,                                       \
          *(const u16x8*)(&Alds[buf][(wm * 4 + m) * 1024 + lane * 16]));       \
    __builtin_amdgcn_s_setprio(1);                                             \
    _Pragma("unroll") for (int m = 0; m < 4; ++m)                              \
      _Pragma("unroll") for (int n = 0; n < 4; ++n)                            \
        acc[m][n] = __builtin_amdgcn_mfma_f32_16x16x32_bf16(bf[n], am[m],      \
                                                            acc[m][n], 0, 0, 0); \
    __builtin_amdgcn_s_setprio(0);                                             \
  } while (0)

  // ---- m97 loop: DMA next tile, compute current, sync (vmcnt0+lgkm0+barrier)
  DMA_TILE(0, 0);
  __syncthreads();
#pragma unroll 1
  for (int kt = 0; kt < NT; ++kt) {
    const int buf = kt & 1;
    if (kt + 1 < NT) DMA_TILE(kt + 1, buf ^ 1);
    COMPUTE(buf);
    __syncthreads();
  }

  // ---- epilogue (transposed fragments, v10-validated): lane owns C row
  // rbase+m*16 and 4 consecutive cols cbase+n*16.. -> f32x4 stores, bias f32x4.
  const int rbase = brow + wm * 64 + (lane & 15);
  const int cbase = bcol + wn * 64 + ((lane >> 4) << 2);
#pragma unroll
  for (int n = 0; n < 4; ++n) {
    const int col = cbase + n * 16;
    const f32x4 bv4 = *(const f32x4*)&Bv[col];
#pragma unroll
    for (int m = 0; m < 4; ++m) {
      const int row = rbase + m * 16;
      f32x4 v = acc[m][n] + bv4;
      *(f32x4*)&C[(size_t)row * ND + col] = v;
    }
  }
}

// ---------------- fallback (ws too small): reg-staged single kernel ----------
__global__ __launch_bounds__(256, 2)
void gemm_fallback(const float* __restrict__ X, const float* __restrict__ W,
                   const float* __restrict__ Bv, float* __restrict__ C) {
  __shared__ __align__(16) unsigned char Asm[2][8192];
  __shared__ __align__(16) unsigned char Bsm[2][8192];
  const int bid = blockIdx.x;
  const int brow = (bid >> 3) * BM, bcol = (bid & 7) * BN;
  const int t = threadIdx.x, lane = t & 63, w = t >> 6;
  const int wm = w >> 1, wn = w & 1;
  const float* gA[2]; const float* gB[2]; int woff[2];
#pragma unroll
  for (int j = 0; j < 2; ++j) {
    int s = t + j * 256, row = s >> 2, kq = s & 3;
    gA[j] = X + (size_t)(brow + row) * KD + kq * 8;
    gB[j] = W + (size_t)(bcol + row) * KD + kq * 8;
    woff[j] = (row >> 4) * 1024 + kq * 256 + (row & 15) * 16;
  }
  f32x4 acc[4][4] = {};
  for (int kt = 0; kt < NT; ++kt) {
    int buf = kt & 1;
#pragma unroll
    for (int j = 0; j < 2; ++j) {
      f32x4 alo = *(const f32x4*)(gA[j] + (size_t)kt * BK);
      f32x4 ahi = *(const f32x4*)(gA[j] + (size_t)kt * BK + 4);
      f32x4 blo = *(const f32x4*)(gB[j] + (size_t)kt * BK);
      f32x4 bhi = *(const f32x4*)(gB[j] + (size_t)kt * BK + 4);
      u16x8 oa, ob;
#pragma unroll
      for (int q = 0; q < 4; ++q) {
        oa[q]   = __builtin_bit_cast(unsigned short, (__bf16)alo[q]);
        oa[4+q] = __builtin_bit_cast(unsigned short, (__bf16)ahi[q]);
        ob[q]   = __builtin_bit_cast(unsigned short, (__bf16)blo[q]);
        ob[4+q] = __builtin_bit_cast(unsigned short, (__bf16)bhi[q]);
      }
      *(u16x8*)&Asm[buf][woff[j]] = oa;
      *(u16x8*)&Bsm[buf][woff[j]] = ob;
    }
    __syncthreads();
    bf16x8 bf[4], am[4];
#pragma unroll
    for (int n = 0; n < 4; ++n)
      bf[n] = __builtin_bit_cast(bf16x8, *(const u16x8*)(&Bsm[buf][(wn*4+n)*1024 + lane*16]));
#pragma unroll
    for (int m = 0; m < 4; ++m)
      am[m] = __builtin_bit_cast(bf16x8, *(const u16x8*)(&Asm[buf][(wm*4+m)*1024 + lane*16]));
#pragma unroll
    for (int m = 0; m < 4; ++m)
#pragma unroll
      for (int n = 0; n < 4; ++n)
        acc[m][n] = __builtin_amdgcn_mfma_f32_16x16x32_bf16(bf[n], am[m], acc[m][n], 0, 0, 0);
    __syncthreads();
  }
  const int rbase = brow + wm * 64 + (lane & 15);
  const int cbase = bcol + wn * 64 + ((lane >> 4) << 2);
#pragma unroll
  for (int n = 0; n < 4; ++n) {
    const int col = cbase + n * 16;
    const f32x4 bv4 = *(const f32x4*)&Bv[col];
#pragma unroll
    for (int m = 0; m < 4; ++m) {
      f32x4 v = acc[m][n] + bv4;
      *(f32x4*)&C[(size_t)(rbase + m * 16) * ND + col] = v;
    }
  }
}

extern "C" void kernel_launch(void* const* d_in, const int* in_sizes, int n_in,
                              void* d_out, int out_size, void* d_ws, size_t ws_size,
                              hipStream_t stream) {
  const float* x = (const float*)d_in[0];   // [8192,1024] f32
  const float* W = (const float*)d_in[1];   // [1024,1024] f32
  const float* b = (const float*)d_in[2];   // [1024] f32
  float* out = (float*)d_out;               // [8192,1024] f32

  if (ws_size >= WS_NEEDED) {
    unsigned short* ws = (unsigned short*)d_ws;
    const int nchunks = (int)((XELEMS + WELEMS) / 8);   // 1179648 = 4608 * 256
    hipLaunchKernelGGL(cvt_bf16, dim3(nchunks / 256), dim3(256), 0, stream, x, W, ws);
    hipLaunchKernelGGL(gemm_dma, dim3((MD / BM) * (ND / BN)), dim3(256), 0, stream,
                       (const unsigned short*)ws, b, out);
  } else {
    hipLaunchKernelGGL(gemm_fallback, dim3((MD / BM) * (ND / BN)), dim3(256), 0,
                       stream, x, W, b, out);
  }
}